// Round 6
// baseline (354.230 us; speedup 1.0000x reference)
//
#include <hip/hip_runtime.h>
#include <cmath>

constexpr int D    = 512;
constexpr int NC   = 225;   // classes
constexpr int NPC  = 224;   // outputs per class
constexpr int NP1  = 256;   // padded W1 column count
constexpr int TB   = 32;    // tokens per chunk

// ws layout (int units)
constexpr int WS_NCHUNK = 0;        // 1
constexpr int WS_CHUNK  = 16;       // 481*4 ints (cls,start,cnt,0)
constexpr int WS_ORDER  = 2048;     // 4096 token ids grouped by class
constexpr int WS_PART1  = 6144;     // 4096*4*4 floats {m,s,e,0} per (tok,oq)
constexpr int WS_PART2  = 71680;    // 4096*4*4 floats
constexpr int WS_B1P    = 137216;   // 256 floats padded b1
constexpr int WS_W1P    = 137472;   // 512*256 floats padded W1

// ---------- prep: histogram + scans + chunk table (phase2 first) + scatter ----------
__global__ __launch_bounds__(256) void k_prep(const int* __restrict__ target,
                                              int* __restrict__ ws, int ntok) {
    __shared__ int h[256];
    __shared__ int sc[256];
    __shared__ int sc2[256];
    __shared__ int cur[NC];
    const int tid = threadIdx.x;
    h[tid] = 0;
    __syncthreads();
    for (int n = tid; n < ntok; n += 256) atomicAdd(&h[target[n] / NPC], 1);
    __syncthreads();
    const int hv = h[tid];
    sc[tid] = hv; __syncthreads();
    for (int o = 1; o < 256; o <<= 1) {
        int a = (tid >= o) ? sc[tid - o] : 0;
        __syncthreads();
        sc[tid] += a;
        __syncthreads();
    }
    const int start = sc[tid] - hv;
    const int nch = (tid < NC) ? (hv + TB - 1) / TB : 0;
    sc2[tid] = nch; __syncthreads();
    for (int o = 1; o < 256; o <<= 1) {
        int a = (tid >= o) ? sc2[tid - o] : 0;
        __syncthreads();
        sc2[tid] += a;
        __syncthreads();
    }
    const int nch2 = sc2[255];                  // total phase-2 chunks
    if (tid < NC) {
        cur[tid] = start;
        const int cb = sc2[tid] - nch;
        for (int j = 0; j < nch; ++j) {
            const int e = WS_CHUNK + (cb + j) * 4;
            ws[e + 0] = tid;
            ws[e + 1] = start + j * TB;
            ws[e + 2] = min(TB, hv - j * TB);
            ws[e + 3] = 0;
        }
    }
    const int P1C = ntok / TB;                  // 128 phase-1 chunks
    if (tid < P1C) {
        const int e = WS_CHUNK + (nch2 + tid) * 4;
        ws[e + 0] = -1;
        ws[e + 1] = tid * TB;
        ws[e + 2] = TB;
        ws[e + 3] = 0;
    }
    if (tid == 0) ws[WS_NCHUNK] = nch2 + P1C;
    __syncthreads();
    for (int n = tid; n < ntok; n += 256) {
        const int c = target[n] / NPC;
        const int pos = atomicAdd(&cur[c], 1);
        ws[WS_ORDER + pos] = n;
    }
}

// ---------- pad W1 (512x225 -> 512x256) and b1 into ws ----------
__global__ __launch_bounds__(256) void k_pad(const float* __restrict__ W1,
                                             const float* __restrict__ b1,
                                             int* __restrict__ ws) {
    float* W1p = (float*)ws + WS_W1P;
    float* b1p = (float*)ws + WS_B1P;
    const int idx = blockIdx.x * 256 + threadIdx.x;
    if (idx < D * NP1) {
        const int d = idx >> 8, c = idx & 255;
        W1p[idx] = (c < NC) ? W1[d * NC + c] : 0.f;
    }
    if (blockIdx.x == 0 && threadIdx.x < NP1)
        b1p[threadIdx.x] = (threadIdx.x < NC) ? b1[threadIdx.x] : 0.f;
}

// ---------- per-chunk GEMM + partial softmax, all in registers ----------
// 128 threads: og = tid&15 (4 cols each), tg = tid>>4 (rows tg+8i, i<NI).
template <int NI, bool PH2>
__device__ __forceinline__ void run_chunk(
    const float* __restrict__ x, const int* __restrict__ target,
    const float* __restrict__ W, const float* __restrict__ bsrc,
    const int* __restrict__ order, float* __restrict__ part,
    int start, int cnt, int oq)
{
    constexpr int NP      = PH2 ? NPC : NP1;
    constexpr int NCREAL  = PH2 ? NPC : NC;
    const int tid = threadIdx.x;
    const int og  = tid & 15;
    const int tg  = tid >> 4;
    const int colbase = oq * 64 + og * 4;
    const int wcol = (PH2 && colbase >= NPC) ? 0 : colbase;   // clamp for safe loads
    const float* wp = W + wcol;

    int toks[NI];
    const float* xp[NI];
    #pragma unroll
    for (int i = 0; i < NI; ++i) {
        const int ridx = min(tg + 8 * i, cnt - 1);
        toks[i] = PH2 ? order[start + ridx] : (start + ridx);
        xp[i] = x + (size_t)toks[i] * D;
    }

    float4 wg[4][4];
    float4 xg[4][NI];
    float  acc[4][NI];
    #pragma unroll
    for (int j = 0; j < 4; ++j)
        #pragma unroll
        for (int i = 0; i < NI; ++i) acc[j][i] = 0.f;

    // prologue: 4 groups (k = 0,4,8,12) in flight
    #pragma unroll
    for (int g = 0; g < 4; ++g) {
        #pragma unroll
        for (int k = 0; k < 4; ++k)
            wg[g][k] = *reinterpret_cast<const float4*>(wp + (size_t)(g * 4 + k) * NP);
        #pragma unroll
        for (int i = 0; i < NI; ++i)
            xg[g][i] = *reinterpret_cast<const float4*>(xp[i] + g * 4);
    }

    #pragma unroll 1
    for (int k0 = 0; k0 < D; k0 += 16) {
        #pragma unroll
        for (int g = 0; g < 4; ++g) {
            // FMA group g (k = k0 + 4g .. +3)
            #pragma unroll
            for (int k = 0; k < 4; ++k) {
                #pragma unroll
                for (int i = 0; i < NI; ++i) {
                    const float xk = (&xg[g][i].x)[k];
                    acc[0][i] = fmaf(xk, wg[g][k].x, acc[0][i]);
                    acc[1][i] = fmaf(xk, wg[g][k].y, acc[1][i]);
                    acc[2][i] = fmaf(xk, wg[g][k].z, acc[2][i]);
                    acc[3][i] = fmaf(xk, wg[g][k].w, acc[3][i]);
                }
            }
            // issue group g for k0+16+4g (wrap keeps addresses valid; masked cost)
            int kn = k0 + 16 + 4 * g;
            kn = (kn >= D) ? (kn - D) : kn;
            #pragma unroll
            for (int k = 0; k < 4; ++k)
                wg[g][k] = *reinterpret_cast<const float4*>(wp + (size_t)(kn + k) * NP);
            #pragma unroll
            for (int i = 0; i < NI; ++i)
                xg[g][i] = *reinterpret_cast<const float4*>(xp[i] + kn);
        }
    }

    // bias (safe: clamped/padded)
    float4 bv = {0.f, 0.f, 0.f, 0.f};
    if (!PH2 || colbase < NPC)
        bv = *reinterpret_cast<const float4*>(bsrc + wcol);

    // per-row partial softmax over this block's 64 columns
    #pragma unroll
    for (int i = 0; i < NI; ++i) {
        float l[4];
        #pragma unroll
        for (int j = 0; j < 4; ++j) {
            const int col = colbase + j;
            l[j] = (col < NCREAL) ? (acc[j][i] + (&bv.x)[j]) : -1e30f;
        }
        float m = fmaxf(fmaxf(l[0], l[1]), fmaxf(l[2], l[3]));
        #pragma unroll
        for (int msk = 8; msk >= 1; msk >>= 1) m = fmaxf(m, __shfl_xor(m, msk, 64));
        float s = __expf(l[0] - m) + __expf(l[1] - m) +
                  __expf(l[2] - m) + __expf(l[3] - m);
        #pragma unroll
        for (int msk = 8; msk >= 1; msk >>= 1) s += __shfl_xor(s, msk, 64);
        const int t = target[toks[i]];
        const int tcol = PH2 ? (t % NPC) : (t / NPC);
        const int dd = tcol - colbase;
        const float lsel = (dd == 0) ? l[0] : (dd == 1) ? l[1] : (dd == 2) ? l[2] : l[3];
        float e = (dd >= 0 && dd < 4) ? __expf(lsel - m) : 0.f;
        #pragma unroll
        for (int msk = 8; msk >= 1; msk >>= 1) e += __shfl_xor(e, msk, 64);
        if (og == 0) {
            float4 rec = {m, s, e, 0.f};
            *reinterpret_cast<float4*>(part + (size_t)toks[i] * 16 + oq * 4) = rec;
        }
    }
}

__global__ __launch_bounds__(128) void k_main(
    const float* __restrict__ x, const int* __restrict__ target,
    const float* __restrict__ W2, const float* __restrict__ b2,
    int* __restrict__ ws)
{
    const int bid = blockIdx.x;
    const int chunkid = bid >> 2;
    const int oq = bid & 3;
    if (chunkid >= ws[WS_NCHUNK]) return;

    const int4 ce = *reinterpret_cast<const int4*>(ws + WS_CHUNK + chunkid * 4);
    const int cls = ce.x, start = ce.y, cnt = ce.z;
    const int* order = ws + WS_ORDER;

    if (cls >= 0) {
        const float* W = W2 + (size_t)cls * D * NPC;
        const float* b = b2 + cls * NPC;
        float* part = (float*)ws + WS_PART2;
        const int NI = (cnt + 7) >> 3;
        switch (NI) {
            case 1: run_chunk<1, true>(x, target, W, b, order, part, start, cnt, oq); break;
            case 2: run_chunk<2, true>(x, target, W, b, order, part, start, cnt, oq); break;
            case 3: run_chunk<3, true>(x, target, W, b, order, part, start, cnt, oq); break;
            default: run_chunk<4, true>(x, target, W, b, order, part, start, cnt, oq); break;
        }
    } else {
        const float* W = (const float*)ws + WS_W1P;
        const float* b = (const float*)ws + WS_B1P;
        float* part = (float*)ws + WS_PART1;
        run_chunk<4, false>(x, target, W, b, order, part, start, cnt, oq);
    }
}

// ---------- combine: merge 4 partials per phase, out = p1*p2 ----------
__global__ __launch_bounds__(256) void k_combine(const int* __restrict__ ws,
                                                 float* __restrict__ out, int ntok) {
    const int n = blockIdx.x * 256 + threadIdx.x;
    if (n >= ntok) return;
    const float4* P1 = reinterpret_cast<const float4*>((const float*)ws + WS_PART1) + n * 4;
    const float4* P2 = reinterpret_cast<const float4*>((const float*)ws + WS_PART2) + n * 4;
    float p[2];
    #pragma unroll
    for (int ph = 0; ph < 2; ++ph) {
        const float4* P = (ph == 0) ? P1 : P2;
        float4 q0 = P[0], q1 = P[1], q2 = P[2], q3 = P[3];
        float M = fmaxf(fmaxf(q0.x, q1.x), fmaxf(q2.x, q3.x));
        float S = q0.y * __expf(q0.x - M) + q1.y * __expf(q1.x - M) +
                  q2.y * __expf(q2.x - M) + q3.y * __expf(q3.x - M);
        float E = q0.z * __expf(q0.x - M) + q1.z * __expf(q1.x - M) +
                  q2.z * __expf(q2.x - M) + q3.z * __expf(q3.x - M);
        p[ph] = E / S;
    }
    out[n] = p[0] * p[1];
}

extern "C" void kernel_launch(void* const* d_in, const int* in_sizes, int n_in,
                              void* d_out, int out_size, void* d_ws, size_t ws_size,
                              hipStream_t stream) {
    const float* x      = (const float*)d_in[0];
    const int*   target = (const int*)  d_in[1];
    const float* W1     = (const float*)d_in[2];
    const float* b1     = (const float*)d_in[3];
    const float* W2     = (const float*)d_in[4];
    const float* b2     = (const float*)d_in[5];
    float* out = (float*)d_out;
    int*   wsi = (int*)d_ws;

    const int ntok = in_sizes[1];                        // 4096
    // chunks: phase2 <= NC + ntok/TB = 353, phase1 = 128 -> 481; x4 output splits
    const int maxgrid = 4 * (NC + ntok / TB + ntok / TB);

    k_prep   <<<1, 256, 0, stream>>>(target, wsi, ntok);
    k_pad    <<<(D * NP1 + 255) / 256, 256, 0, stream>>>(W1, b1, wsi);
    k_main   <<<maxgrid, 128, 0, stream>>>(x, target, W2, b2, wsi);
    k_combine<<<(ntok + 255) / 256, 256, 0, stream>>>(wsi, out, ntok);
}

// Round 7
// 122.418 us; speedup vs baseline: 2.8936x; 2.8936x over previous
//
#include <hip/hip_runtime.h>
#include <cmath>

constexpr int D    = 512;
constexpr int NC   = 225;   // classes
constexpr int NPC  = 224;   // outputs per class
constexpr int NP1  = 232;   // padded W1 columns
constexpr int TB2  = 32;    // tokens per phase-2 class chunk
constexpr int TB1  = 16;    // tokens per phase-1 chunk
constexpr int KH   = 256;   // phase-2 K half

// ws layout (int units)
constexpr int WS_NCHUNK = 0;        // 1
constexpr int WS_CHUNK  = 16;       // 962*4 ints (cls,start,cnt,kq)
constexpr int WS_ORDER  = 4096;     // 4096 token ids grouped by class
constexpr int WS_P1     = 8192;     // 4096 floats p1
constexpr int WS_B1P    = 12288;    // 232 floats padded b1
constexpr int WS_W1P    = 12544;    // 512*232 floats padded W1
constexpr int WS_PART2  = 131584;   // 2*4096*224 floats partial dots

// ---------- prep: histogram + scans + chunk table (phase2 x2 kq first) + scatter ----------
__global__ __launch_bounds__(256) void k_prep(const int* __restrict__ target,
                                              int* __restrict__ ws, int ntok) {
    __shared__ int h[256];
    __shared__ int sc[256];
    __shared__ int sc2[256];
    __shared__ int cur[NC];
    const int tid = threadIdx.x;
    h[tid] = 0;
    __syncthreads();
    for (int n = tid; n < ntok; n += 256) atomicAdd(&h[target[n] / NPC], 1);
    __syncthreads();
    const int hv = h[tid];
    sc[tid] = hv; __syncthreads();
    for (int o = 1; o < 256; o <<= 1) {
        int a = (tid >= o) ? sc[tid - o] : 0;
        __syncthreads();
        sc[tid] += a;
        __syncthreads();
    }
    const int start = sc[tid] - hv;
    const int nch = (tid < NC) ? (hv + TB2 - 1) / TB2 : 0;
    sc2[tid] = nch; __syncthreads();
    for (int o = 1; o < 256; o <<= 1) {
        int a = (tid >= o) ? sc2[tid - o] : 0;
        __syncthreads();
        sc2[tid] += a;
        __syncthreads();
    }
    const int nch2 = sc2[255];                  // phase-2 class chunks
    if (tid < NC) {
        cur[tid] = start;
        const int cb = sc2[tid] - nch;
        for (int j = 0; j < nch; ++j) {
            for (int q = 0; q < 2; ++q) {
                const int e = WS_CHUNK + ((cb + j) * 2 + q) * 4;
                ws[e + 0] = tid;
                ws[e + 1] = start + j * TB2;
                ws[e + 2] = min(TB2, hv - j * TB2);
                ws[e + 3] = q;
            }
        }
    }
    const int P1C = ntok / TB1;                 // 256 phase-1 chunks
    if (tid < P1C) {
        const int e = WS_CHUNK + (nch2 * 2 + tid) * 4;
        ws[e + 0] = -1;
        ws[e + 1] = tid * TB1;
        ws[e + 2] = TB1;
        ws[e + 3] = 0;
    }
    if (tid == 0) ws[WS_NCHUNK] = nch2 * 2 + P1C;
    __syncthreads();
    for (int n = tid; n < ntok; n += 256) {
        const int c = target[n] / NPC;
        const int pos = atomicAdd(&cur[c], 1);
        ws[WS_ORDER + pos] = n;
    }
}

// ---------- pad W1 (512x225 -> 512x232) and b1 into ws ----------
__global__ __launch_bounds__(256) void k_pad(const float* __restrict__ W1,
                                             const float* __restrict__ b1,
                                             int* __restrict__ ws) {
    float* W1p = (float*)ws + WS_W1P;
    float* b1p = (float*)ws + WS_B1P;
    const int idx = blockIdx.x * 256 + threadIdx.x;
    if (idx < D * NP1) {
        const int d = idx / NP1, c = idx % NP1;
        W1p[idx] = (c < NC) ? W1[d * NC + c] : 0.f;
    }
    if (blockIdx.x == 0 && threadIdx.x < NP1)
        b1p[threadIdx.x] = (threadIdx.x < NC) ? b1[threadIdx.x] : -1e30f;
}

// ---------- phase 1: full-K GEMM + softmax -> p1 ----------
__device__ __forceinline__ void run_p1(
    const float* __restrict__ x, const int* __restrict__ target,
    int* __restrict__ ws, float* __restrict__ sd, int* __restrict__ stok, int start)
{
    const float* W  = (const float*)ws + WS_W1P;
    const float* bp = (const float*)ws + WS_B1P;
    float* p1 = (float*)ws + WS_P1;
    const int tid = threadIdx.x;
    if (tid < TB1) stok[tid] = start + tid;
    __syncthreads();
    #pragma unroll
    for (int k = 0; k < 8; ++k) {
        const int f = tid + k * 256;
        const int row = f >> 7, col = f & 127;
        *reinterpret_cast<float4*>(&sd[row * 528 + col * 4]) =
            reinterpret_cast<const float4*>(x + (size_t)stok[row] * D)[col];
    }
    __syncthreads();

    const int og = tid % 29, tg = tid / 29;
    const bool active = (tg < 8);
    float acc[8][2];
    #pragma unroll
    for (int j = 0; j < 8; ++j) { acc[j][0] = 0.f; acc[j][1] = 0.f; }

    if (active) {
        const float* wp = W + og * 8;
        float4 wl0[4], wh0[4], wl1[4], wh1[4], xa[2], xb[2];
        #pragma unroll
        for (int k = 0; k < 4; ++k) {
            wl0[k] = *reinterpret_cast<const float4*>(wp + (size_t)k * NP1);
            wh0[k] = *reinterpret_cast<const float4*>(wp + (size_t)k * NP1 + 4);
        }
        #pragma unroll
        for (int i = 0; i < 2; ++i)
            xa[i] = *reinterpret_cast<const float4*>(&sd[(tg + 8 * i) * 528]);
        for (int d0 = 0; d0 < D; d0 += 8) {
            #pragma unroll
            for (int k = 0; k < 4; ++k) {
                wl1[k] = *reinterpret_cast<const float4*>(wp + (size_t)(k + 4) * NP1);
                wh1[k] = *reinterpret_cast<const float4*>(wp + (size_t)(k + 4) * NP1 + 4);
            }
            #pragma unroll
            for (int i = 0; i < 2; ++i)
                xb[i] = *reinterpret_cast<const float4*>(&sd[(tg + 8 * i) * 528 + d0 + 4]);
            #pragma unroll
            for (int k = 0; k < 4; ++k)
                #pragma unroll
                for (int i = 0; i < 2; ++i) {
                    const float xk = (&xa[i].x)[k];
                    acc[0][i] = fmaf(xk, wl0[k].x, acc[0][i]);
                    acc[1][i] = fmaf(xk, wl0[k].y, acc[1][i]);
                    acc[2][i] = fmaf(xk, wl0[k].z, acc[2][i]);
                    acc[3][i] = fmaf(xk, wl0[k].w, acc[3][i]);
                    acc[4][i] = fmaf(xk, wh0[k].x, acc[4][i]);
                    acc[5][i] = fmaf(xk, wh0[k].y, acc[5][i]);
                    acc[6][i] = fmaf(xk, wh0[k].z, acc[6][i]);
                    acc[7][i] = fmaf(xk, wh0[k].w, acc[7][i]);
                }
            if (d0 + 8 < D) {
                #pragma unroll
                for (int k = 0; k < 4; ++k) {
                    wl0[k] = *reinterpret_cast<const float4*>(wp + (size_t)(k + 8) * NP1);
                    wh0[k] = *reinterpret_cast<const float4*>(wp + (size_t)(k + 8) * NP1 + 4);
                }
                #pragma unroll
                for (int i = 0; i < 2; ++i)
                    xa[i] = *reinterpret_cast<const float4*>(&sd[(tg + 8 * i) * 528 + d0 + 8]);
            }
            #pragma unroll
            for (int k = 0; k < 4; ++k)
                #pragma unroll
                for (int i = 0; i < 2; ++i) {
                    const float xk = (&xb[i].x)[k];
                    acc[0][i] = fmaf(xk, wl1[k].x, acc[0][i]);
                    acc[1][i] = fmaf(xk, wl1[k].y, acc[1][i]);
                    acc[2][i] = fmaf(xk, wl1[k].z, acc[2][i]);
                    acc[3][i] = fmaf(xk, wl1[k].w, acc[3][i]);
                    acc[4][i] = fmaf(xk, wh1[k].x, acc[4][i]);
                    acc[5][i] = fmaf(xk, wh1[k].y, acc[5][i]);
                    acc[6][i] = fmaf(xk, wh1[k].z, acc[6][i]);
                    acc[7][i] = fmaf(xk, wh1[k].w, acc[7][i]);
                }
            wp += 8 * NP1;
        }
    }
    __syncthreads();
    if (active) {
        const float4 bl = *reinterpret_cast<const float4*>(bp + og * 8);
        const float4 bh = *reinterpret_cast<const float4*>(bp + og * 8 + 4);
        #pragma unroll
        for (int i = 0; i < 2; ++i) {
            const int row = tg + 8 * i;
            float4 lo = {acc[0][i] + bl.x, acc[1][i] + bl.y, acc[2][i] + bl.z, acc[3][i] + bl.w};
            float4 hi = {acc[4][i] + bh.x, acc[5][i] + bh.y, acc[6][i] + bh.z, acc[7][i] + bh.w};
            *reinterpret_cast<float4*>(&sd[row * 528 + og * 8])     = lo;
            *reinterpret_cast<float4*>(&sd[row * 528 + og * 8 + 4]) = hi;
        }
    }
    __syncthreads();
    const int wv = tid >> 6, ln = tid & 63;
    #pragma unroll
    for (int s = 0; s < 4; ++s) {
        const int t = wv * 4 + s;
        float v0 = sd[t * 528 + ln];
        float v1 = sd[t * 528 + 64 + ln];
        float v2 = sd[t * 528 + 128 + ln];
        float v3 = (192 + ln < NP1) ? sd[t * 528 + 192 + ln] : -1e30f;
        float m = fmaxf(fmaxf(v0, v1), fmaxf(v2, v3));
        #pragma unroll
        for (int k = 32; k >= 1; k >>= 1) m = fmaxf(m, __shfl_xor(m, k, 64));
        float e = __expf(v0 - m) + __expf(v1 - m) + __expf(v2 - m) +
                  ((192 + ln < NP1) ? __expf(v3 - m) : 0.f);
        #pragma unroll
        for (int k = 32; k >= 1; k >>= 1) e += __shfl_xor(e, k, 64);
        if (ln == 0) {
            const int tok = start + t;
            const int cls = target[tok] / NPC;
            p1[tok] = __expf(sd[t * 528 + cls] - m) / e;
        }
    }
}

// ---------- phase 2: half-K GEMM -> raw partial dots ----------
template <int NI>
__device__ __forceinline__ void run_p2(
    const float* __restrict__ x, const float* __restrict__ W2,
    int* __restrict__ ws, float* __restrict__ sd, int* __restrict__ stok,
    int cls, int start, int cnt, int kq, int ntok)
{
    const int tid = threadIdx.x;
    float* part2 = (float*)ws + WS_PART2;
    if (tid < TB2) stok[tid] = ws[WS_ORDER + start + min(tid, cnt - 1)];
    __syncthreads();
    #pragma unroll
    for (int k = 0; k < 8; ++k) {
        const int f = tid + k * 256;
        const int row = f >> 6, col = f & 63;
        *reinterpret_cast<float4*>(&sd[row * 264 + col * 4]) =
            reinterpret_cast<const float4*>(x + (size_t)stok[row] * D + kq * KH)[col];
    }
    __syncthreads();

    const int og = tid % 28, tg = tid / 28;
    const bool active = (tg < 8);
    float acc[8][NI];
    #pragma unroll
    for (int j = 0; j < 8; ++j)
        #pragma unroll
        for (int i = 0; i < NI; ++i) acc[j][i] = 0.f;

    if (active) {
        const float* wp = W2 + (size_t)cls * D * NPC + (size_t)(kq * KH) * NPC + og * 8;
        float4 wl0[4], wh0[4], wl1[4], wh1[4], xa[NI], xb[NI];
        #pragma unroll
        for (int k = 0; k < 4; ++k) {
            wl0[k] = *reinterpret_cast<const float4*>(wp + (size_t)k * NPC);
            wh0[k] = *reinterpret_cast<const float4*>(wp + (size_t)k * NPC + 4);
        }
        #pragma unroll
        for (int i = 0; i < NI; ++i)
            xa[i] = *reinterpret_cast<const float4*>(&sd[(tg + 8 * i) * 264]);
        for (int d0 = 0; d0 < KH; d0 += 8) {
            #pragma unroll
            for (int k = 0; k < 4; ++k) {
                wl1[k] = *reinterpret_cast<const float4*>(wp + (size_t)(k + 4) * NPC);
                wh1[k] = *reinterpret_cast<const float4*>(wp + (size_t)(k + 4) * NPC + 4);
            }
            #pragma unroll
            for (int i = 0; i < NI; ++i)
                xb[i] = *reinterpret_cast<const float4*>(&sd[(tg + 8 * i) * 264 + d0 + 4]);
            #pragma unroll
            for (int k = 0; k < 4; ++k)
                #pragma unroll
                for (int i = 0; i < NI; ++i) {
                    const float xk = (&xa[i].x)[k];
                    acc[0][i] = fmaf(xk, wl0[k].x, acc[0][i]);
                    acc[1][i] = fmaf(xk, wl0[k].y, acc[1][i]);
                    acc[2][i] = fmaf(xk, wl0[k].z, acc[2][i]);
                    acc[3][i] = fmaf(xk, wl0[k].w, acc[3][i]);
                    acc[4][i] = fmaf(xk, wh0[k].x, acc[4][i]);
                    acc[5][i] = fmaf(xk, wh0[k].y, acc[5][i]);
                    acc[6][i] = fmaf(xk, wh0[k].z, acc[6][i]);
                    acc[7][i] = fmaf(xk, wh0[k].w, acc[7][i]);
                }
            if (d0 + 8 < KH) {
                #pragma unroll
                for (int k = 0; k < 4; ++k) {
                    wl0[k] = *reinterpret_cast<const float4*>(wp + (size_t)(k + 8) * NPC);
                    wh0[k] = *reinterpret_cast<const float4*>(wp + (size_t)(k + 8) * NPC + 4);
                }
                #pragma unroll
                for (int i = 0; i < NI; ++i)
                    xa[i] = *reinterpret_cast<const float4*>(&sd[(tg + 8 * i) * 264 + d0 + 8]);
            }
            #pragma unroll
            for (int k = 0; k < 4; ++k)
                #pragma unroll
                for (int i = 0; i < NI; ++i) {
                    const float xk = (&xb[i].x)[k];
                    acc[0][i] = fmaf(xk, wl1[k].x, acc[0][i]);
                    acc[1][i] = fmaf(xk, wl1[k].y, acc[1][i]);
                    acc[2][i] = fmaf(xk, wl1[k].z, acc[2][i]);
                    acc[3][i] = fmaf(xk, wl1[k].w, acc[3][i]);
                    acc[4][i] = fmaf(xk, wh1[k].x, acc[4][i]);
                    acc[5][i] = fmaf(xk, wh1[k].y, acc[5][i]);
                    acc[6][i] = fmaf(xk, wh1[k].z, acc[6][i]);
                    acc[7][i] = fmaf(xk, wh1[k].w, acc[7][i]);
                }
            wp += 8 * NPC;
        }
        // write raw partial dots (bias added in combine)
        #pragma unroll
        for (int i = 0; i < NI; ++i) {
            const int row = tg + 8 * i;
            const int tok = stok[row];
            float* base = part2 + ((size_t)kq * ntok + tok) * NPC + og * 8;
            float4 lo = {acc[0][i], acc[1][i], acc[2][i], acc[3][i]};
            float4 hi = {acc[4][i], acc[5][i], acc[6][i], acc[7][i]};
            *reinterpret_cast<float4*>(base)     = lo;
            *reinterpret_cast<float4*>(base + 4) = hi;
        }
    }
}

__global__ __launch_bounds__(256) void k_main(
    const float* __restrict__ x, const int* __restrict__ target,
    const float* __restrict__ W2, int* __restrict__ ws, int ntok)
{
    __shared__ float sd[8448];
    __shared__ int stok[32];
    const int bid = blockIdx.x;
    if (bid >= ws[WS_NCHUNK]) return;
    const int4 ce = *reinterpret_cast<const int4*>(ws + WS_CHUNK + bid * 4);
    if (ce.x >= 0) {
        switch ((ce.z + 7) >> 3) {
            case 1:  run_p2<1>(x, W2, ws, sd, stok, ce.x, ce.y, ce.z, ce.w, ntok); break;
            case 2:  run_p2<2>(x, W2, ws, sd, stok, ce.x, ce.y, ce.z, ce.w, ntok); break;
            case 3:  run_p2<3>(x, W2, ws, sd, stok, ce.x, ce.y, ce.z, ce.w, ntok); break;
            default: run_p2<4>(x, W2, ws, sd, stok, ce.x, ce.y, ce.z, ce.w, ntok); break;
        }
    } else {
        run_p1(x, target, ws, sd, stok, ce.y);
    }
}

// ---------- combine: sum K-halves + bias, softmax, out = p1*p2 ----------
__global__ __launch_bounds__(256) void k_combine(
    const int* __restrict__ target, const float* __restrict__ b2,
    const int* __restrict__ ws, float* __restrict__ out, int ntok)
{
    __shared__ float ls[16][228];
    const int b = blockIdx.x, tid = threadIdx.x;
    const float* part2 = (const float*)ws + WS_PART2;
    const float* p1 = (const float*)ws + WS_P1;
    #pragma unroll
    for (int t = 0; t < 16; ++t) {
        const int tok = b * 16 + t;
        const int cls = target[tok] / NPC;
        if (tid < NPC)
            ls[t][tid] = part2[(size_t)tok * NPC + tid] +
                         part2[((size_t)ntok + tok) * NPC + tid] +
                         b2[cls * NPC + tid];
    }
    __syncthreads();
    const int wv = tid >> 6, ln = tid & 63;
    #pragma unroll
    for (int s = 0; s < 4; ++s) {
        const int t = wv * 4 + s;
        const int tok = b * 16 + t;
        float v0 = ls[t][ln];
        float v1 = ls[t][64 + ln];
        float v2 = ls[t][128 + ln];
        float v3 = (192 + ln < NPC) ? ls[t][192 + ln] : -1e30f;
        float m = fmaxf(fmaxf(v0, v1), fmaxf(v2, v3));
        #pragma unroll
        for (int k = 32; k >= 1; k >>= 1) m = fmaxf(m, __shfl_xor(m, k, 64));
        float e = __expf(v0 - m) + __expf(v1 - m) + __expf(v2 - m) +
                  ((192 + ln < NPC) ? __expf(v3 - m) : 0.f);
        #pragma unroll
        for (int k = 32; k >= 1; k >>= 1) e += __shfl_xor(e, k, 64);
        if (ln == 0) {
            const int ii = target[tok] % NPC;
            out[tok] = p1[tok] * (__expf(ls[t][ii] - m) / e);
        }
    }
}

extern "C" void kernel_launch(void* const* d_in, const int* in_sizes, int n_in,
                              void* d_out, int out_size, void* d_ws, size_t ws_size,
                              hipStream_t stream) {
    const float* x      = (const float*)d_in[0];
    const int*   target = (const int*)  d_in[1];
    const float* W1     = (const float*)d_in[2];
    const float* b1     = (const float*)d_in[3];
    const float* W2     = (const float*)d_in[4];
    const float* b2     = (const float*)d_in[5];
    float* out = (float*)d_out;
    int*   wsi = (int*)d_ws;

    const int ntok = in_sizes[1];   // 4096
    // phase2 entries <= 2*(NC + ntok/TB2), phase1 = ntok/TB1
    const int maxgrid = 2 * (NC + ntok / TB2) + ntok / TB1;   // 962

    k_prep   <<<1, 256, 0, stream>>>(target, wsi, ntok);
    k_pad    <<<(D * NP1 + 255) / 256, 256, 0, stream>>>(W1, b1, wsi);
    k_main   <<<maxgrid, 256, 0, stream>>>(x, target, W2, wsi, ntok);
    k_combine<<<ntok / 16, 256, 0, stream>>>(target, b2, wsi, out, ntok);
}

// Round 8
// 83.641 us; speedup vs baseline: 4.2351x; 1.4636x over previous
//
#include <hip/hip_runtime.h>
#include <cmath>

constexpr int D    = 512;
constexpr int NC   = 225;   // classes
constexpr int NPC  = 224;   // outputs per class
constexpr int NP1  = 232;   // padded W1 columns
constexpr int TB   = 32;    // tokens per chunk (both phases)
constexpr int KH   = 256;   // K half
constexpr int XST  = 260;   // x LDS row stride (floats): 4-quad rotation per row

// ws layout (int units)
constexpr int WS_NCHUNK = 0;                        // 1
constexpr int WS_CHUNK  = 16;                       // 962*4 ints (cls,start,cnt,kq)
constexpr int WS_ORDER  = 4096;                     // 4096 token ids grouped by class
constexpr int WS_W1P    = 8192;                     // 512*232 floats padded W1
constexpr int WS_PART1  = WS_W1P + D * NP1;         // 2*4096*232 floats raw dots
constexpr int WS_PART2  = WS_PART1 + 2 * 4096 * NP1;// 2*4096*224 floats raw dots

// ---------- prep: histogram + scans + chunk table (p2 halves first) + scatter ----------
__global__ __launch_bounds__(256) void k_prep(const int* __restrict__ target,
                                              int* __restrict__ ws, int ntok) {
    __shared__ int h[256];
    __shared__ int sc[256];
    __shared__ int sc2[256];
    __shared__ int cur[NC];
    const int tid = threadIdx.x;
    h[tid] = 0;
    __syncthreads();
    for (int n = tid; n < ntok; n += 256) atomicAdd(&h[target[n] / NPC], 1);
    __syncthreads();
    const int hv = h[tid];
    sc[tid] = hv; __syncthreads();
    for (int o = 1; o < 256; o <<= 1) {
        int a = (tid >= o) ? sc[tid - o] : 0;
        __syncthreads();
        sc[tid] += a;
        __syncthreads();
    }
    const int start = sc[tid] - hv;
    const int nch = (tid < NC) ? (hv + TB - 1) / TB : 0;
    sc2[tid] = nch; __syncthreads();
    for (int o = 1; o < 256; o <<= 1) {
        int a = (tid >= o) ? sc2[tid - o] : 0;
        __syncthreads();
        sc2[tid] += a;
        __syncthreads();
    }
    const int nch2 = sc2[255];                  // phase-2 class chunks
    if (tid < NC) {
        cur[tid] = start;
        const int cb = sc2[tid] - nch;
        for (int j = 0; j < nch; ++j) {
            for (int q = 0; q < 2; ++q) {
                const int e = WS_CHUNK + ((cb + j) * 2 + q) * 4;
                ws[e + 0] = tid;
                ws[e + 1] = start + j * TB;
                ws[e + 2] = min(TB, hv - j * TB);
                ws[e + 3] = q;
            }
        }
    }
    const int P1C = ntok / TB;                  // 128 phase-1 chunks
    if (tid < P1C) {
        for (int q = 0; q < 2; ++q) {
            const int e = WS_CHUNK + (nch2 * 2 + tid * 2 + q) * 4;
            ws[e + 0] = -1;
            ws[e + 1] = tid * TB;
            ws[e + 2] = TB;
            ws[e + 3] = q;
        }
    }
    if (tid == 0) ws[WS_NCHUNK] = nch2 * 2 + P1C * 2;
    __syncthreads();
    for (int n = tid; n < ntok; n += 256) {
        const int c = target[n] / NPC;
        const int pos = atomicAdd(&cur[c], 1);
        ws[WS_ORDER + pos] = n;
    }
}

// ---------- pad W1 (512x225 -> 512x232, zeros) into ws ----------
__global__ __launch_bounds__(256) void k_pad(const float* __restrict__ W1,
                                             int* __restrict__ ws) {
    float* W1p = (float*)ws + WS_W1P;
    const int idx = blockIdx.x * 256 + threadIdx.x;
    if (idx < D * NP1) {
        const int d = idx / NP1, c = idx % NP1;
        W1p[idx] = (c < NC) ? W1[d * NC + c] : 0.f;
    }
}

// ---------- half-K GEMM -> raw partial dots (no bias, no softmax) ----------
// 256 threads: og = tid % OGD (8 cols), tg = tid / OGD (rows tg+8i, i<NI).
template <int NI, bool PH2>
__device__ __forceinline__ void run_gemm(
    const float* __restrict__ x, const float* __restrict__ wbase,
    const int* __restrict__ order, float* __restrict__ part,
    float* __restrict__ xs, int* __restrict__ stok,
    int start, int cnt, int kq, int ntok)
{
    constexpr int NP  = PH2 ? NPC : NP1;   // W row stride & partial stride
    constexpr int OGD = NP / 8;            // 28 or 29
    const int tid = threadIdx.x;

    if (tid < TB)
        stok[tid] = PH2 ? order[start + min(tid, cnt - 1)] : (start + tid);
    __syncthreads();

    // stage 32 x-rows x 256 cols (2048 float4, 8 per thread, coalesced)
    #pragma unroll
    for (int k = 0; k < 8; ++k) {
        const int f = tid + k * 256;
        const int row = f >> 6, col = f & 63;
        *reinterpret_cast<float4*>(&xs[row * XST + col * 4]) =
            reinterpret_cast<const float4*>(x + (size_t)stok[row] * D + kq * KH)[col];
    }
    __syncthreads();

    const int og = tid % OGD, tg = tid / OGD;
    if (tg >= 8) return;

    float acc[8][NI];
    #pragma unroll
    for (int j = 0; j < 8; ++j)
        #pragma unroll
        for (int i = 0; i < NI; ++i) acc[j][i] = 0.f;

    const float* wp = wbase + og * 8;
    float4 wl0[4], wh0[4], wl1[4], wh1[4], xa[NI], xb[NI];
    #pragma unroll
    for (int k = 0; k < 4; ++k) {
        wl0[k] = *reinterpret_cast<const float4*>(wp + (size_t)k * NP);
        wh0[k] = *reinterpret_cast<const float4*>(wp + (size_t)k * NP + 4);
    }
    #pragma unroll
    for (int i = 0; i < NI; ++i)
        xa[i] = *reinterpret_cast<const float4*>(&xs[(tg + 8 * i) * XST]);

    for (int d0 = 0; d0 < KH; d0 += 8) {
        #pragma unroll
        for (int k = 0; k < 4; ++k) {
            wl1[k] = *reinterpret_cast<const float4*>(wp + (size_t)(k + 4) * NP);
            wh1[k] = *reinterpret_cast<const float4*>(wp + (size_t)(k + 4) * NP + 4);
        }
        #pragma unroll
        for (int i = 0; i < NI; ++i)
            xb[i] = *reinterpret_cast<const float4*>(&xs[(tg + 8 * i) * XST + d0 + 4]);
        #pragma unroll
        for (int k = 0; k < 4; ++k)
            #pragma unroll
            for (int i = 0; i < NI; ++i) {
                const float xk = (&xa[i].x)[k];
                acc[0][i] = fmaf(xk, wl0[k].x, acc[0][i]);
                acc[1][i] = fmaf(xk, wl0[k].y, acc[1][i]);
                acc[2][i] = fmaf(xk, wl0[k].z, acc[2][i]);
                acc[3][i] = fmaf(xk, wl0[k].w, acc[3][i]);
                acc[4][i] = fmaf(xk, wh0[k].x, acc[4][i]);
                acc[5][i] = fmaf(xk, wh0[k].y, acc[5][i]);
                acc[6][i] = fmaf(xk, wh0[k].z, acc[6][i]);
                acc[7][i] = fmaf(xk, wh0[k].w, acc[7][i]);
            }
        if (d0 + 8 < KH) {
            #pragma unroll
            for (int k = 0; k < 4; ++k) {
                wl0[k] = *reinterpret_cast<const float4*>(wp + (size_t)(k + 8) * NP);
                wh0[k] = *reinterpret_cast<const float4*>(wp + (size_t)(k + 8) * NP + 4);
            }
            #pragma unroll
            for (int i = 0; i < NI; ++i)
                xa[i] = *reinterpret_cast<const float4*>(&xs[(tg + 8 * i) * XST + d0 + 8]);
        }
        #pragma unroll
        for (int k = 0; k < 4; ++k)
            #pragma unroll
            for (int i = 0; i < NI; ++i) {
                const float xk = (&xb[i].x)[k];
                acc[0][i] = fmaf(xk, wl1[k].x, acc[0][i]);
                acc[1][i] = fmaf(xk, wl1[k].y, acc[1][i]);
                acc[2][i] = fmaf(xk, wl1[k].z, acc[2][i]);
                acc[3][i] = fmaf(xk, wl1[k].w, acc[3][i]);
                acc[4][i] = fmaf(xk, wh1[k].x, acc[4][i]);
                acc[5][i] = fmaf(xk, wh1[k].y, acc[5][i]);
                acc[6][i] = fmaf(xk, wh1[k].z, acc[6][i]);
                acc[7][i] = fmaf(xk, wh1[k].w, acc[7][i]);
            }
        wp += 8 * NP;
    }

    // write raw partial dots for this K-half
    #pragma unroll
    for (int i = 0; i < NI; ++i) {
        const int tok = stok[tg + 8 * i];
        float* base = part + ((size_t)kq * ntok + tok) * NP + og * 8;
        float4 lo = {acc[0][i], acc[1][i], acc[2][i], acc[3][i]};
        float4 hi = {acc[4][i], acc[5][i], acc[6][i], acc[7][i]};
        *reinterpret_cast<float4*>(base)     = lo;
        *reinterpret_cast<float4*>(base + 4) = hi;
    }
}

__global__ __launch_bounds__(256) void k_main(
    const float* __restrict__ x, const float* __restrict__ W2,
    int* __restrict__ ws, int ntok)
{
    __shared__ float xs[TB * XST];
    __shared__ int stok[TB];
    const int bid = blockIdx.x;
    if (bid >= ws[WS_NCHUNK]) return;
    const int4 ce = *reinterpret_cast<const int4*>(ws + WS_CHUNK + bid * 4);
    const int cls = ce.x, start = ce.y, cnt = ce.z, kq = ce.w;
    const int* order = ws + WS_ORDER;

    if (cls >= 0) {
        const float* wb = W2 + (size_t)cls * D * NPC + (size_t)kq * KH * NPC;
        float* part = (float*)ws + WS_PART2;
        switch ((cnt + 7) >> 3) {
            case 1:  run_gemm<1, true>(x, wb, order, part, xs, stok, start, cnt, kq, ntok); break;
            case 2:  run_gemm<2, true>(x, wb, order, part, xs, stok, start, cnt, kq, ntok); break;
            case 3:  run_gemm<3, true>(x, wb, order, part, xs, stok, start, cnt, kq, ntok); break;
            default: run_gemm<4, true>(x, wb, order, part, xs, stok, start, cnt, kq, ntok); break;
        }
    } else {
        const float* wb = (const float*)ws + WS_W1P + (size_t)kq * KH * NP1;
        float* part = (float*)ws + WS_PART1;
        run_gemm<4, false>(x, wb, order, part, xs, stok, start, cnt, kq, ntok);
    }
}

// ---------- combine: sum K-halves + bias -> two softmaxes -> out ----------
__device__ __forceinline__ float softmax_prob(
    const float* __restrict__ part, int tok, int ntok, int stride, int ncols,
    const float* __restrict__ bias, int tcol, int ln)
{
    float v[4];
    #pragma unroll
    for (int j = 0; j < 4; ++j) {
        const int col = ln + 64 * j;
        v[j] = (col < ncols)
             ? (part[(size_t)tok * stride + col] +
                part[((size_t)ntok + tok) * stride + col] + bias[col])
             : -1e30f;
    }
    float m = fmaxf(fmaxf(v[0], v[1]), fmaxf(v[2], v[3]));
    #pragma unroll
    for (int k = 32; k >= 1; k >>= 1) m = fmaxf(m, __shfl_xor(m, k, 64));
    float s = 0.f, e = 0.f;
    #pragma unroll
    for (int j = 0; j < 4; ++j) {
        const int col = ln + 64 * j;
        const float ex = (col < ncols) ? __expf(v[j] - m) : 0.f;
        s += ex;
        if (col == tcol) e = ex;
    }
    #pragma unroll
    for (int k = 32; k >= 1; k >>= 1) {
        s += __shfl_xor(s, k, 64);
        e += __shfl_xor(e, k, 64);
    }
    return e / s;
}

__global__ __launch_bounds__(256) void k_combine(
    const int* __restrict__ target, const float* __restrict__ b1,
    const float* __restrict__ b2, const int* __restrict__ ws,
    float* __restrict__ out, int ntok)
{
    const int tid = threadIdx.x;
    const int wv = tid >> 6, ln = tid & 63;
    const float* part1 = (const float*)ws + WS_PART1;
    const float* part2 = (const float*)ws + WS_PART2;
    #pragma unroll
    for (int s = 0; s < 4; ++s) {
        const int tok = blockIdx.x * 16 + wv * 4 + s;
        if (tok >= ntok) continue;
        const int tt  = target[tok];
        const int cls = tt / NPC;
        const float p1 = softmax_prob(part1, tok, ntok, NP1, NC,  b1, cls, ln);
        const float p2 = softmax_prob(part2, tok, ntok, NPC, NPC, b2 + cls * NPC, tt % NPC, ln);
        if (ln == 0) out[tok] = p1 * p2;
    }
}

extern "C" void kernel_launch(void* const* d_in, const int* in_sizes, int n_in,
                              void* d_out, int out_size, void* d_ws, size_t ws_size,
                              hipStream_t stream) {
    const float* x      = (const float*)d_in[0];
    const int*   target = (const int*)  d_in[1];
    const float* W1     = (const float*)d_in[2];
    const float* b1     = (const float*)d_in[3];
    const float* W2     = (const float*)d_in[4];
    const float* b2     = (const float*)d_in[5];
    float* out = (float*)d_out;
    int*   wsi = (int*)d_ws;

    const int ntok = in_sizes[1];   // 4096
    // p2 entries <= 2*(NC + ntok/TB), p1 = 2*(ntok/TB)
    const int maxgrid = 2 * (NC + ntok / TB) + 2 * (ntok / TB);   // 962

    k_prep   <<<1, 256, 0, stream>>>(target, wsi, ntok);
    k_pad    <<<(D * NP1 + 255) / 256, 256, 0, stream>>>(W1, wsi);
    k_main   <<<maxgrid, 256, 0, stream>>>(x, W2, wsi, ntok);
    k_combine<<<(ntok + 15) / 16, 256, 0, stream>>>(target, b1, b2, wsi, out, ntok);
}

// Round 9
// 64.010 us; speedup vs baseline: 5.5340x; 1.3067x over previous
//
#include <hip/hip_runtime.h>
#include <cmath>

typedef _Float16 half8 __attribute__((ext_vector_type(8)));
typedef float f32x4 __attribute__((ext_vector_type(4)));

constexpr int D    = 512;
constexpr int NC   = 225;   // classes
constexpr int NPC  = 224;   // outputs per class
constexpr int N1   = 256;   // padded W1 cols
constexpr int TB   = 32;    // tokens per chunk
constexpr int KT   = 32;    // K-tile = one MFMA K step
constexpr int WST  = 40;    // LDS fp16 row stride (80 B: 16B-aligned, 2-way-free)
constexpr int LST  = 260;   // logits LDS row stride (f32)

// ws layout (int units)
constexpr int WS_NCHUNK = 0;
constexpr int WS_CHUNK  = 16;       // 481*4 ints (cls,start,cnt,0)
constexpr int WS_ORDER  = 4096;     // 4096 ids grouped by class
constexpr int WS_P1     = 8192;     // 4096 floats
constexpr int WS_P2     = 12288;    // 4096 floats
constexpr int WS_B1P    = 16384;    // 256 floats padded b1
constexpr int WS_W1P    = 16640;    // 512*256 floats padded W1

// ---------- prep: histogram + scans + chunk table (p2 first) + scatter ----------
__global__ __launch_bounds__(256) void k_prep(const int* __restrict__ target,
                                              int* __restrict__ ws, int ntok) {
    __shared__ int h[256], sc[256], sc2[256], cur[NC];
    const int tid = threadIdx.x;
    h[tid] = 0;
    __syncthreads();
    for (int n = tid; n < ntok; n += 256) atomicAdd(&h[target[n] / NPC], 1);
    __syncthreads();
    const int hv = h[tid];
    sc[tid] = hv; __syncthreads();
    for (int o = 1; o < 256; o <<= 1) {
        int a = (tid >= o) ? sc[tid - o] : 0;
        __syncthreads();
        sc[tid] += a;
        __syncthreads();
    }
    const int start = sc[tid] - hv;
    const int nch = (tid < NC) ? (hv + TB - 1) / TB : 0;
    sc2[tid] = nch; __syncthreads();
    for (int o = 1; o < 256; o <<= 1) {
        int a = (tid >= o) ? sc2[tid - o] : 0;
        __syncthreads();
        sc2[tid] += a;
        __syncthreads();
    }
    const int nch2 = sc2[255];
    if (tid < NC) {
        cur[tid] = start;
        const int cb = sc2[tid] - nch;
        for (int j = 0; j < nch; ++j) {
            const int e = WS_CHUNK + (cb + j) * 4;
            ws[e + 0] = tid;
            ws[e + 1] = start + j * TB;
            ws[e + 2] = min(TB, hv - j * TB);
            ws[e + 3] = 0;
        }
    }
    const int P1C = ntok / TB;      // 128
    if (tid < P1C) {
        const int e = WS_CHUNK + (nch2 + tid) * 4;
        ws[e + 0] = -1;
        ws[e + 1] = tid * TB;
        ws[e + 2] = TB;
        ws[e + 3] = 0;
    }
    if (tid == 0) ws[WS_NCHUNK] = nch2 + P1C;
    __syncthreads();
    for (int n = tid; n < ntok; n += 256) {
        const int c = target[n] / NPC;
        const int pos = atomicAdd(&cur[c], 1);
        ws[WS_ORDER + pos] = n;
    }
}

// ---------- pad W1 (512x225 -> 512x256 zeros) + b1 into ws ----------
__global__ __launch_bounds__(256) void k_pad(const float* __restrict__ W1,
                                             const float* __restrict__ b1,
                                             int* __restrict__ ws) {
    float* W1p = (float*)ws + WS_W1P;
    float* b1p = (float*)ws + WS_B1P;
    const int idx = blockIdx.x * 256 + threadIdx.x;
    if (idx < D * N1) {
        const int d = idx >> 8, c = idx & 255;
        W1p[idx] = (c < NC) ? W1[d * NC + c] : 0.f;
    }
    if (blockIdx.x == 0 && threadIdx.x < N1)
        b1p[threadIdx.x] = (threadIdx.x < NC) ? b1[threadIdx.x] : 0.f;
}

// fp16 split: hi = RTN(v), flushed to 0 if subnormal; lo = RTN((v-hi)*2048)
__device__ __forceinline__ void f16split(float v, _Float16& h, _Float16& l) {
    _Float16 hh = (_Float16)v;
    float hf = (float)hh;
    if (fabsf(hf) < 6.104e-5f) { hh = (_Float16)0.f; hf = 0.f; }
    h = hh;
    l = (_Float16)((v - hf) * 2048.0f);
}

// ---------- main: per-chunk fp16-split MFMA GEMM + softmax ----------
// 256 threads (4 waves). M = cols (14 or 16 tiles), N = 32 tokens (2 tiles).
template <bool PH2>
__device__ __forceinline__ void run_chunk(
    const float* __restrict__ x, const int* __restrict__ target,
    const float* __restrict__ Wsrc, const float* __restrict__ bsrc,
    int* __restrict__ ws, char* smem, int start, int cnt)
{
    constexpr int NP    = PH2 ? NPC : N1;    // cols / W row stride
    constexpr int COLG  = NP / 4;            // 56 / 64
    constexpr int NREAL = PH2 ? NPC : NC;
    const int tid  = threadIdx.x;
    const int w    = tid >> 6;
    const int lane = tid & 63;
    const int l15  = lane & 15, l4 = lane >> 4;

    _Float16* Wh = (_Float16*)smem;                 // [256][40]
    _Float16* Wl = (_Float16*)(smem + 20480);       // [256][40]
    _Float16* xh = (_Float16*)(smem + 40960);       // [32][40]
    _Float16* xl = (_Float16*)(smem + 43520);       // [32][40]
    int* stok    = (int*)(smem + 46080);            // [32]
    float* ls    = (float*)smem;                    // [32][260] (aliases Wh/Wl)

    if (tid < TB)
        stok[tid] = PH2 ? ws[WS_ORDER + start + min(tid, cnt - 1)] : (start + tid);
    __syncthreads();

    f32x4 accA[4][2] = {};   // hi*hi
    f32x4 accB[4][2] = {};   // hi*lo' + lo'*hi  (scaled x2048)

    const int cg = PH2 ? (tid % 56) : (tid & 63);
    const int kg = PH2 ? (tid / 56) : (tid >> 6);
    const bool wact = (!PH2) || (tid < 224);
    const int xtok = tid >> 2, xkg = tid & 3;

    for (int kt = 0; kt < D / KT; ++kt) {
        const int k0 = kt * KT;
        // ---- convert W tile [32 k x NP cols] into [col][k] fp16 h/l ----
        if (wact) {
            #pragma unroll
            for (int s = 0; s < 4; ++s) {
                const int c = cg + COLG * s;
                half8 hv, lv;
                #pragma unroll
                for (int j = 0; j < 8; ++j) {
                    const float v = Wsrc[(size_t)(k0 + kg * 8 + j) * NP + c];
                    _Float16 hq, lq;
                    f16split(v, hq, lq);
                    hv[j] = hq; lv[j] = lq;
                }
                *(half8*)(Wh + c * WST + kg * 8) = hv;
                *(half8*)(Wl + c * WST + kg * 8) = lv;
            }
        }
        // ---- convert x tile [32 tok x 32 k] ----
        if (tid < 128) {
            const float* xr = x + (size_t)stok[xtok] * D + k0 + xkg * 8;
            const float4 va = *(const float4*)(xr);
            const float4 vb = *(const float4*)(xr + 4);
            float v[8] = {va.x, va.y, va.z, va.w, vb.x, vb.y, vb.z, vb.w};
            half8 hv, lv;
            #pragma unroll
            for (int j = 0; j < 8; ++j) {
                _Float16 hq, lq;
                f16split(v[j], hq, lq);
                hv[j] = hq; lv[j] = lq;
            }
            *(half8*)(xh + xtok * WST + xkg * 8) = hv;
            *(half8*)(xl + xtok * WST + xkg * 8) = lv;
        }
        __syncthreads();
        // ---- MFMA: 7 (p2) / 8 (p1) C-tiles per wave, 3 mfma each ----
        half8 Bh[2], Bl[2];
        #pragma unroll
        for (int n = 0; n < 2; ++n) {
            Bh[n] = *(const half8*)(xh + (n * 16 + l15) * WST + l4 * 8);
            Bl[n] = *(const half8*)(xl + (n * 16 + l15) * WST + l4 * 8);
        }
        #pragma unroll
        for (int mi = 0; mi < 4; ++mi) {
            const int m = PH2 ? ((7 * w) >> 1) + mi : 4 * w + mi;
            const half8 Ah = *(const half8*)(Wh + (m * 16 + l15) * WST + l4 * 8);
            const half8 Al = *(const half8*)(Wl + (m * 16 + l15) * WST + l4 * 8);
            #pragma unroll
            for (int n = 0; n < 2; ++n) {
                bool valid = true;
                if (PH2) { const int ct = 2 * m + n; valid = (ct >= 7 * w) && (ct < 7 * w + 7); }
                if (valid) {
                    accA[mi][n] = __builtin_amdgcn_mfma_f32_16x16x32_f16(Ah, Bh[n], accA[mi][n], 0, 0, 0);
                    accB[mi][n] = __builtin_amdgcn_mfma_f32_16x16x32_f16(Ah, Bl[n], accB[mi][n], 0, 0, 0);
                    accB[mi][n] = __builtin_amdgcn_mfma_f32_16x16x32_f16(Al, Bh[n], accB[mi][n], 0, 0, 0);
                }
            }
        }
        __syncthreads();
    }

    // ---- epilogue: combine accs + bias -> ls[tok][col] ----
    #pragma unroll
    for (int mi = 0; mi < 4; ++mi) {
        const int m = PH2 ? ((7 * w) >> 1) + mi : 4 * w + mi;
        const int col0 = m * 16 + l4 * 4;
        #pragma unroll
        for (int n = 0; n < 2; ++n) {
            bool valid = true;
            if (PH2) { const int ct = 2 * m + n; valid = (ct >= 7 * w) && (ct < 7 * w + 7); }
            if (valid) {
                const float4 bv = *(const float4*)(bsrc + col0);
                f32x4 r;
                r[0] = accA[mi][n][0] + accB[mi][n][0] * (1.f / 2048.f) + bv.x;
                r[1] = accA[mi][n][1] + accB[mi][n][1] * (1.f / 2048.f) + bv.y;
                r[2] = accA[mi][n][2] + accB[mi][n][2] * (1.f / 2048.f) + bv.z;
                r[3] = accA[mi][n][3] + accB[mi][n][3] * (1.f / 2048.f) + bv.w;
                const int tok = n * 16 + l15;
                *(f32x4*)(ls + tok * LST + col0) = r;
            }
        }
    }
    __syncthreads();

    // ---- softmax per token (R4-proven pattern) ----
    float* pout = (float*)ws + (PH2 ? WS_P2 : WS_P1);
    #pragma unroll
    for (int s = 0; s < 8; ++s) {
        const int t = w * 8 + s;
        const float v0 = ls[t * LST + lane];
        const float v1 = ls[t * LST + 64 + lane];
        const float v2 = ls[t * LST + 128 + lane];
        const float v3 = (192 + lane < NREAL) ? ls[t * LST + 192 + lane] : -1e30f;
        float mx = fmaxf(fmaxf(v0, v1), fmaxf(v2, v3));
        #pragma unroll
        for (int k = 32; k >= 1; k >>= 1) mx = fmaxf(mx, __shfl_xor(mx, k, 64));
        float e = __expf(v0 - mx) + __expf(v1 - mx) + __expf(v2 - mx) +
                  ((192 + lane < NREAL) ? __expf(v3 - mx) : 0.f);
        #pragma unroll
        for (int k = 32; k >= 1; k >>= 1) e += __shfl_xor(e, k, 64);
        if (lane == 0 && t < cnt) {
            const int tok = stok[t];
            const int tt  = target[tok];
            const int col = PH2 ? (tt % NPC) : (tt / NPC);
            pout[tok] = __expf(ls[t * LST + col] - mx) / e;
        }
    }
}

__global__ __launch_bounds__(256) void k_main(
    const float* __restrict__ x, const int* __restrict__ target,
    const float* __restrict__ W2, const float* __restrict__ b2,
    int* __restrict__ ws)
{
    __shared__ __align__(16) char smem[46208];
    const int bid = blockIdx.x;
    if (bid >= ws[WS_NCHUNK]) return;
    const int4 ce = *(const int4*)(ws + WS_CHUNK + bid * 4);
    if (ce.x >= 0) {
        run_chunk<true>(x, target, W2 + (size_t)ce.x * D * NPC, b2 + ce.x * NPC,
                        ws, smem, ce.y, ce.z);
    } else {
        run_chunk<false>(x, target, (const float*)ws + WS_W1P, (const float*)ws + WS_B1P,
                         ws, smem, ce.y, ce.z);
    }
}

// ---------- combine: out = p1 * p2 ----------
__global__ __launch_bounds__(256) void k_combine(const int* __restrict__ ws,
                                                 float* __restrict__ out, int ntok) {
    const int n = blockIdx.x * 256 + threadIdx.x;
    const float* p1 = (const float*)ws + WS_P1;
    const float* p2 = (const float*)ws + WS_P2;
    if (n < ntok) out[n] = p1[n] * p2[n];
}

extern "C" void kernel_launch(void* const* d_in, const int* in_sizes, int n_in,
                              void* d_out, int out_size, void* d_ws, size_t ws_size,
                              hipStream_t stream) {
    const float* x      = (const float*)d_in[0];
    const int*   target = (const int*)  d_in[1];
    const float* W1     = (const float*)d_in[2];
    const float* b1     = (const float*)d_in[3];
    const float* W2     = (const float*)d_in[4];
    const float* b2     = (const float*)d_in[5];
    float* out = (float*)d_out;
    int*   wsi = (int*)d_ws;

    const int ntok = in_sizes[1];   // 4096
    const int maxgrid = (NC + ntok / TB) + ntok / TB;   // 481

    k_prep   <<<1, 256, 0, stream>>>(target, wsi, ntok);
    k_pad    <<<(D * N1 + 255) / 256, 256, 0, stream>>>(W1, b1, wsi);
    k_main   <<<maxgrid, 256, 0, stream>>>(x, target, W2, b2, wsi);
    k_combine<<<(ntok + 255) / 256, 256, 0, stream>>>(wsi, out, ntok);
}